// Round 1
// baseline (900.262 us; speedup 1.0000x reference)
//
#include <hip/hip_runtime.h>
#include <math.h>

#define ALPHA 0.2f
#define THRESH 0.5f

constexpr int B = 32, N = 1024, C = 64;

// Kernel A: h = input @ W ; s_src = h @ a_src ; s_dst = h @ a_dst
// One wave per row (4 rows / 256-thread block). W staged in LDS.
__global__ __launch_bounds__(256) void gat_hs(const float* __restrict__ input,
                                              const float* __restrict__ Wm,
                                              const float* __restrict__ a,
                                              float* __restrict__ h,
                                              float* __restrict__ ssrc,
                                              float* __restrict__ sdst)
{
    __shared__ float Ws[64 * 64];
    __shared__ float ins[4][64];
    const int tid  = threadIdx.x;
    const int lane = tid & 63;
    const int wave = tid >> 6;
    const int row  = blockIdx.x * 4 + wave;

    for (int i = tid; i < 64 * 64; i += 256) Ws[i] = Wm[i];
    ins[wave][lane] = input[row * 64 + lane];
    __syncthreads();

    float hc = 0.f;
#pragma unroll
    for (int k = 0; k < 64; ++k)
        hc = fmaf(ins[wave][k], Ws[k * 64 + lane], hc);

    h[row * 64 + lane] = hc;

    float vs = hc * a[lane];        // a_src = a[0:64]
    float vd = hc * a[64 + lane];   // a_dst = a[64:128]
#pragma unroll
    for (int off = 32; off; off >>= 1) {
        vs += __shfl_down(vs, off, 64);
        vd += __shfl_down(vd, off, 64);
    }
    if (lane == 0) { ssrc[row] = vs; sdst[row] = vd; }
}

// Kernel B: per (b,i): masked softmax over j fused with h_prime = att @ h, then ELU.
// 256 threads = 4 waves; wave w owns j in [w*256, (w+1)*256).
__global__ __launch_bounds__(256) void gat_attn(const float* __restrict__ adj,
                                                const float* __restrict__ h,
                                                const float* __restrict__ ssrc,
                                                const float* __restrict__ sdst,
                                                float* __restrict__ out)
{
    const int bi   = blockIdx.x;       // b*N + i
    const int b    = bi >> 10;
    const int i    = bi & 1023;
    const int tid  = threadIdx.x;
    const int lane = tid & 63;
    const int wave = tid >> 6;

    const float* __restrict__ adjrow = adj + (size_t)i * N;
    const float* __restrict__ sd     = sdst + b * N;
    const float* __restrict__ hb     = h + (size_t)b * N * C;
    const float  si = ssrc[bi];

    // ---- pass 1: masked max of s_dst over the row (lrelu is monotonic) ----
    float m = -INFINITY;
    for (int j = tid; j < N; j += 256) {
        float av = adjrow[j];
        float s  = sd[j];
        if (av > THRESH) m = fmaxf(m, s);
    }
#pragma unroll
    for (int off = 32; off; off >>= 1) m = fmaxf(m, __shfl_down(m, off, 64));
    __shared__ float redm[4];
    if (lane == 0) redm[wave] = m;
    __syncthreads();
    m = fmaxf(fmaxf(redm[0], redm[1]), fmaxf(redm[2], redm[3]));
    float mi = si + m;
    mi = mi > 0.f ? mi : ALPHA * mi;   // row max of masked e

    // ---- pass 2: p = exp(lrelu(si+sd[j]) - mi) on masked j; acc += p * h[j,:] ----
    float acc  = 0.f;
    float psum = 0.f;
    const int jbase0 = wave * 256;
    for (int jt = 0; jt < 256; jt += 64) {
        const int jbase = jbase0 + jt;
        float av = adjrow[jbase + lane];
        float e  = si + sd[jbase + lane];
        e = e > 0.f ? e : ALPHA * e;
        float p = (av > THRESH) ? __expf(e - mi) : 0.f;
        psum += p;
#pragma unroll
        for (int jj = 0; jj < 64; ++jj) {
            float pj = __shfl(p, jj, 64);
            if (pj != 0.f)   // wave-uniform: skip ~50% masked-out h loads
                acc = fmaf(pj, hb[(size_t)(jbase + jj) * C + lane], acc);
        }
    }

#pragma unroll
    for (int off = 32; off; off >>= 1) psum += __shfl_down(psum, off, 64);

    __shared__ float accs[4][64];
    __shared__ float psums[4];
    accs[wave][lane] = acc;
    if (lane == 0) psums[wave] = psum;
    __syncthreads();

    if (wave == 0) {
        float at = accs[0][lane] + accs[1][lane] + accs[2][lane] + accs[3][lane];
        float ps = psums[0] + psums[1] + psums[2] + psums[3];
        float hp = at / ps;
        float o  = hp > 0.f ? hp : (__expf(hp * 1.4426950408889634f) - 1.f); // elu; __expf is exp2-based? no:
        // __expf(x) computes e^x; keep it simple and exact:
        o = hp > 0.f ? hp : (__expf(hp) - 1.f);
        out[(size_t)bi * C + lane] = o;
    }
}

extern "C" void kernel_launch(void* const* d_in, const int* in_sizes, int n_in,
                              void* d_out, int out_size, void* d_ws, size_t ws_size,
                              hipStream_t stream) {
    const float* input = (const float*)d_in[0];
    const float* adj   = (const float*)d_in[1];
    const float* Wm    = (const float*)d_in[2];
    const float* a     = (const float*)d_in[3];
    float* out = (float*)d_out;

    float* h    = (float*)d_ws;                 // B*N*C floats = 8 MB
    float* ssrc = h + (size_t)B * N * C;        // B*N floats
    float* sdst = ssrc + (size_t)B * N;         // B*N floats

    gat_hs<<<B * N / 4, 256, 0, stream>>>(input, Wm, a, h, ssrc, sdst);
    gat_attn<<<B * N, 256, 0, stream>>>(adj, h, ssrc, sdst, out);
}

// Round 2
// 253.703 us; speedup vs baseline: 3.5485x; 3.5485x over previous
//
#include <hip/hip_runtime.h>
#include <math.h>

#define ALPHA 0.2f
#define THRESH 0.5f

constexpr int B = 32, N = 1024, C = 64;
constexpr int TI = 16;          // i-rows per block
constexpr int TJ = 64;          // j-tile
constexpr int NTILES = N / TJ;  // 16

// ---------------- Kernel A: h = input@W, s_src = h@a_src, s_dst = h@a_dst ----
// 16 rows per block, 256 threads (4 waves, 4 rows each). W staged in LDS.
__global__ __launch_bounds__(256) void gat_hs(const float* __restrict__ input,
                                              const float* __restrict__ Wm,
                                              const float* __restrict__ a,
                                              float* __restrict__ h,
                                              float* __restrict__ ssrc,
                                              float* __restrict__ sdst)
{
    __shared__ __align__(16) float Ws[64 * 64];   // 16 KB
    __shared__ __align__(16) float ins[16 * 64];  // 4 KB
    const int tid  = threadIdx.x;
    const int lane = tid & 63;
    const int wave = tid >> 6;
    const int row0 = blockIdx.x * 16;

#pragma unroll
    for (int s = 0; s < 4; ++s)
        ((float4*)Ws)[tid + 256 * s] = ((const float4*)Wm)[tid + 256 * s];
    ((float4*)ins)[tid] = ((const float4*)(input + (size_t)row0 * 64))[tid];
    __syncthreads();

    float acc[4] = {0.f, 0.f, 0.f, 0.f};
    for (int k = 0; k < 64; k += 4) {
        float w0 = Ws[(k + 0) * 64 + lane];
        float w1 = Ws[(k + 1) * 64 + lane];
        float w2 = Ws[(k + 2) * 64 + lane];
        float w3 = Ws[(k + 3) * 64 + lane];
#pragma unroll
        for (int q = 0; q < 4; ++q) {
            const float4 iv = *(const float4*)&ins[(wave * 4 + q) * 64 + k];
            acc[q] = fmaf(iv.x, w0, acc[q]);
            acc[q] = fmaf(iv.y, w1, acc[q]);
            acc[q] = fmaf(iv.z, w2, acc[q]);
            acc[q] = fmaf(iv.w, w3, acc[q]);
        }
    }

    const float as = a[lane];
    const float ad = a[64 + lane];
#pragma unroll
    for (int q = 0; q < 4; ++q) {
        const int row = row0 + wave * 4 + q;
        h[(size_t)row * 64 + lane] = acc[q];
        float vs = acc[q] * as;
        float vd = acc[q] * ad;
#pragma unroll
        for (int off = 32; off; off >>= 1) {
            vs += __shfl_down(vs, off, 64);
            vd += __shfl_down(vd, off, 64);
        }
        if (lane == 0) { ssrc[row] = vs; sdst[row] = vd; }
    }
}

// ---------------- Kernel B: fused masked softmax + PV + ELU --------------
// Block = (i_tile of 16, b). 256 threads. grid ordered so b is in the low 5
// bits (XCD round-robin keeps each XCD's L2 on ~4 h-slabs).
__global__ __launch_bounds__(256) void gat_attn(const float* __restrict__ adj,
                                                const float* __restrict__ h,
                                                const float* __restrict__ ssrc,
                                                const float* __restrict__ sdst,
                                                float* __restrict__ out)
{
    __shared__ __align__(16) float h_s[TJ * 64];   // 16 KB (reused as reduction buf)
    __shared__ __align__(16) float p_s[TI * TJ];   // 4 KB

    const int tid  = threadIdx.x;
    const int lane = tid & 63;
    const int wave = tid >> 6;
    const int b    = blockIdx.x & 31;
    const int i0   = (blockIdx.x >> 5) * TI;

    const float* __restrict__ adjb = adj + (size_t)i0 * N;
    const float* __restrict__ sd   = sdst + b * N;
    const float* __restrict__ hb   = h + (size_t)b * N * C;

    // s_src for the 4 rows this (wave,q) owns: ii = wave + 4q
    float ssq[4];
#pragma unroll
    for (int q = 0; q < 4; ++q) ssq[q] = ssrc[b * N + i0 + wave + 4 * q];

    // ---- pass 1: masked max of s_dst per row (lrelu monotonic) ----
    float mp[4] = {-INFINITY, -INFINITY, -INFINITY, -INFINITY};
    for (int k = 0; k < 16; ++k) {
        const int j = k * 64 + lane;
        const float sdv = sd[j];
#pragma unroll
        for (int q = 0; q < 4; ++q) {
            const float av = adjb[(size_t)(wave + 4 * q) * N + j];
            if (av > THRESH) mp[q] = fmaxf(mp[q], sdv);
        }
    }
    float miq[4];
#pragma unroll
    for (int q = 0; q < 4; ++q) {
#pragma unroll
        for (int off = 32; off; off >>= 1)
            mp[q] = fmaxf(mp[q], __shfl_xor(mp[q], off, 64));
        float m = ssq[q] + mp[q];
        miq[q] = m > 0.f ? m : ALPHA * m;   // masked row max of e
    }

    // ---- main loop over j-tiles ----
    float acc[16];
#pragma unroll
    for (int ii = 0; ii < 16; ++ii) acc[ii] = 0.f;
    float psum[4] = {0.f, 0.f, 0.f, 0.f};

    for (int jt = 0; jt < NTILES; ++jt) {
        __syncthreads();   // previous tile's PV reads done

        // stage h tile: 16 KB contiguous
        const float4* hg = (const float4*)(hb + (size_t)jt * TJ * 64);
#pragma unroll
        for (int s = 0; s < 4; ++s)
            ((float4*)h_s)[tid + 256 * s] = hg[tid + 256 * s];

        // compute p tile (16 x 64), accumulate row sums
        {
            const int j = jt * 64 + lane;
            const float sdv = sd[j];
#pragma unroll
            for (int q = 0; q < 4; ++q) {
                const int ii = wave + 4 * q;
                const float av = adjb[(size_t)ii * N + j];
                float e = ssq[q] + sdv;
                e = e > 0.f ? e : ALPHA * e;
                const float p = (av > THRESH) ? __expf(e - miq[q]) : 0.f;
                p_s[ii * TJ + lane] = p;
                psum[q] += p;
            }
        }
        __syncthreads();

        // PV: wave owns j-strip [wave*16, wave*16+16), all 16 ii, c = lane
        const int jb0 = wave * 16;
#pragma unroll
        for (int u = 0; u < 4; ++u) {
            const int jb = jb0 + u * 4;
            const float h0 = h_s[(jb + 0) * 64 + lane];
            const float h1 = h_s[(jb + 1) * 64 + lane];
            const float h2 = h_s[(jb + 2) * 64 + lane];
            const float h3 = h_s[(jb + 3) * 64 + lane];
#pragma unroll
            for (int ii = 0; ii < 16; ++ii) {
                const float4 pv = *(const float4*)&p_s[ii * TJ + jb];
                acc[ii] = fmaf(pv.x, h0, acc[ii]);
                acc[ii] = fmaf(pv.y, h1, acc[ii]);
                acc[ii] = fmaf(pv.z, h2, acc[ii]);
                acc[ii] = fmaf(pv.w, h3, acc[ii]);
            }
        }
    }

    // ---- reduce psum across lanes (all lanes get total for their q rows) ----
#pragma unroll
    for (int q = 0; q < 4; ++q)
#pragma unroll
        for (int off = 32; off; off >>= 1)
            psum[q] += __shfl_xor(psum[q], off, 64);

    // ---- cross-wave reduction of acc via h_s reuse: red[4][16][64] ----
    __syncthreads();   // last PV reads of h_s done
#pragma unroll
    for (int ii = 0; ii < 16; ++ii)
        h_s[wave * 1024 + ii * 64 + lane] = acc[ii];
    __syncthreads();

#pragma unroll
    for (int q = 0; q < 4; ++q) {
        const int ii = wave + 4 * q;
        const float sum = h_s[0 * 1024 + ii * 64 + lane]
                        + h_s[1 * 1024 + ii * 64 + lane]
                        + h_s[2 * 1024 + ii * 64 + lane]
                        + h_s[3 * 1024 + ii * 64 + lane];
        const float hp = sum / psum[q];
        const float o  = hp > 0.f ? hp : (__expf(hp) - 1.f);
        out[((size_t)b * N + i0 + ii) * 64 + lane] = o;
    }
}

extern "C" void kernel_launch(void* const* d_in, const int* in_sizes, int n_in,
                              void* d_out, int out_size, void* d_ws, size_t ws_size,
                              hipStream_t stream) {
    const float* input = (const float*)d_in[0];
    const float* adj   = (const float*)d_in[1];
    const float* Wm    = (const float*)d_in[2];
    const float* a     = (const float*)d_in[3];
    float* out = (float*)d_out;

    float* h    = (float*)d_ws;                 // B*N*C floats = 8 MB
    float* ssrc = h + (size_t)B * N * C;        // B*N
    float* sdst = ssrc + (size_t)B * N;         // B*N

    gat_hs<<<B * N / 16, 256, 0, stream>>>(input, Wm, a, h, ssrc, sdst);
    gat_attn<<<(N / TI) * B, 256, 0, stream>>>(adj, h, ssrc, sdst, out);
}

// Round 3
// 96.827 us; speedup vs baseline: 9.2977x; 2.6202x over previous
//
#include <hip/hip_runtime.h>
#include <math.h>

#define ALPHA 0.2f

constexpr int B = 32, N = 1024, C = 64;
constexpr int TI = 16;          // i-rows per attn block
constexpr int TJ = 64;          // j-tile

typedef __attribute__((ext_vector_type(8))) short short8;
typedef __attribute__((ext_vector_type(4))) float floatx4;

static __device__ __forceinline__ unsigned f32bf(float f) {
    unsigned u = __float_as_uint(f);
    return (u + 0x7FFFu + ((u >> 16) & 1u)) >> 16;   // RNE, no NaN inputs here
}

// ---------------- Kernel M: adj -> bitmask; also wa = W @ a_src/a_dst -----
__global__ __launch_bounds__(256) void gat_mask(const float* __restrict__ adj,
                                                const float* __restrict__ Wm,
                                                const float* __restrict__ a,
                                                unsigned long long* __restrict__ mask64,
                                                float* __restrict__ wa)
{
    const int lane = threadIdx.x & 63;
    const int wave = threadIdx.x >> 6;
    const int id   = blockIdx.x * 4 + wave;      // 0..16383
    const int i    = id >> 4;
    const int jc   = id & 15;
    const float av = adj[(size_t)i * N + jc * 64 + lane];
    const unsigned long long bal = __ballot(av > 0.5f);
    if (lane == 0) mask64[i * 16 + jc] = bal;

    if (blockIdx.x == 0 && wave == 0) {          // wa[k] = sum_c W[k][c]*a[c]
        float accs = 0.f, accd = 0.f;
#pragma unroll
        for (int c4 = 0; c4 < 16; ++c4) {
            const float4 wv = *(const float4*)&Wm[lane * 64 + c4 * 4];
            const float4 as = *(const float4*)&a[c4 * 4];
            const float4 ad = *(const float4*)&a[64 + c4 * 4];
            accs = fmaf(wv.x, as.x, fmaf(wv.y, as.y, fmaf(wv.z, as.z, fmaf(wv.w, as.w, accs))));
            accd = fmaf(wv.x, ad.x, fmaf(wv.y, ad.y, fmaf(wv.z, ad.z, fmaf(wv.w, ad.w, accd))));
        }
        wa[lane] = accs;
        wa[64 + lane] = accd;
    }
}

// ---------------- Kernel A: hT(bf16) = (input@W)^T per batch; s vectors ----
// 64 rows per block. W held in 64 VGPRs/lane; input rows via uniform LDS reads.
__global__ __launch_bounds__(256) void gat_hs(const float* __restrict__ input,
                                              const float* __restrict__ Wm,
                                              const float* __restrict__ wa,
                                              unsigned short* __restrict__ hT,
                                              float* __restrict__ ssrc,
                                              float* __restrict__ sdst)
{
    __shared__ __align__(16) float ins[64 * 68];          // padded rows
    __shared__ __align__(16) unsigned short hsT[64 * 72]; // [c][row] padded
    __shared__ float red_s[256], red_d[256];
    __shared__ float wa_l[128];

    const int tid  = threadIdx.x;
    const int lane = tid & 63;
    const int wave = tid >> 6;
    const int row0 = blockIdx.x * 64;
    const int b    = row0 >> 10;
    const int jb   = row0 & 1023;

    float wreg[64];
#pragma unroll
    for (int k = 0; k < 64; ++k) wreg[k] = Wm[k * 64 + lane];   // W[:,lane]

    const float4* gin = (const float4*)(input + (size_t)row0 * 64);
#pragma unroll
    for (int s = 0; s < 4; ++s) {
        const int id = tid + 256 * s;
        *(float4*)&ins[(id >> 4) * 68 + (id & 15) * 4] = gin[id];
    }
    if (tid < 128) wa_l[tid] = wa[tid];
    __syncthreads();

    // h rows: wave handles rows [wave*16, wave*16+16)
    for (int r = 0; r < 16; ++r) {
        const int row = wave * 16 + r;
        float acc = 0.f;
#pragma unroll
        for (int k4 = 0; k4 < 16; ++k4) {
            const float4 iv = *(const float4*)&ins[row * 68 + k4 * 4];   // uniform
            acc = fmaf(iv.x, wreg[k4 * 4 + 0], acc);
            acc = fmaf(iv.y, wreg[k4 * 4 + 1], acc);
            acc = fmaf(iv.z, wreg[k4 * 4 + 2], acc);
            acc = fmaf(iv.w, wreg[k4 * 4 + 3], acc);
        }
        hsT[lane * 72 + row] = (unsigned short)f32bf(acc);   // transpose in LDS
    }

    // s_src/s_dst = ins @ wa (exact fp32, independent of bf16 h)
    {
        const int r = tid & 63, kq = tid >> 6;
        float as = 0.f, ad = 0.f;
#pragma unroll
        for (int t = 0; t < 4; ++t) {
            const float4 iv = *(const float4*)&ins[r * 68 + kq * 16 + t * 4];
            const float4 ws = *(const float4*)&wa_l[kq * 16 + t * 4];
            const float4 wd = *(const float4*)&wa_l[64 + kq * 16 + t * 4];
            as = fmaf(iv.x, ws.x, fmaf(iv.y, ws.y, fmaf(iv.z, ws.z, fmaf(iv.w, ws.w, as))));
            ad = fmaf(iv.x, wd.x, fmaf(iv.y, wd.y, fmaf(iv.z, wd.z, fmaf(iv.w, wd.w, ad))));
        }
        red_s[tid] = as;
        red_d[tid] = ad;
    }
    __syncthreads();

    if (tid < 64) {
        ssrc[row0 + tid] = red_s[tid] + red_s[tid + 64] + red_s[tid + 128] + red_s[tid + 192];
        sdst[row0 + tid] = red_d[tid] + red_d[tid + 64] + red_d[tid + 128] + red_d[tid + 192];
    }

    // hT global store: thread (c = tid>>2, part = tid&3) writes 32 B
    {
        const int c = tid >> 2, part = tid & 3;
        const short8 v0 = *(const short8*)&hsT[c * 72 + part * 16];
        const short8 v1 = *(const short8*)&hsT[c * 72 + part * 16 + 8];
        const size_t g = ((size_t)(b * 64 + c)) * 1024 + jb + part * 16;
        *(short8*)&hT[g] = v0;
        *(short8*)&hT[g + 8] = v1;
    }
}

// ---------------- Kernel B: fused softmax(no-shift) + MFMA PV + ELU --------
__global__ __launch_bounds__(256) void gat_attn(const unsigned short* __restrict__ hTg,
                                                const float* __restrict__ ssrc,
                                                const float* __restrict__ sdst,
                                                const unsigned* __restrict__ mask32,
                                                float* __restrict__ out)
{
    __shared__ __align__(16) unsigned short h_u[64 * 64];  // 8 KB, chunk-swizzled [c][j]
    __shared__ __align__(16) unsigned short p_u[16 * 64];  // 2 KB, chunk-swizzled [i][j]
    __shared__ float psum_s[16];

    const int tid  = threadIdx.x;
    const int lane = tid & 63;
    const int wave = tid >> 6;
    const int b    = blockIdx.x & 31;
    const int i0   = (blockIdx.x >> 5) * TI;

    const int ii = tid >> 4;          // p-compute row 0..15
    const int jq = tid & 15;          // j-quad 0..15
    const float ssq = ssrc[b * N + i0 + ii];
    const unsigned short* hTb = hTg + (size_t)b * 64 * 1024;
    const float* sd = sdst + b * N;
    const unsigned* mrow = mask32 + (size_t)(i0 + ii) * 32;

    // staging coords: thread (c = tid>>2, m2 = tid&3) stages 32 B of hT
    const int c = tid >> 2, m2 = tid & 3;
    const int hw0 = c * 64 + (((m2 * 2)    ) ^ (c & 7)) * 8;
    const int hw1 = c * 64 + (((m2 * 2 + 1)) ^ (c & 7)) * 8;
    const int pwi = ii * 64 + ((jq >> 1) ^ (ii & 7)) * 8 + (jq & 1) * 4;
    // frag coords
    const int fa_ii = lane & 15, fq = lane >> 4;
    const int cB = wave * 16 + (lane & 15);

    floatx4 acc = {0.f, 0.f, 0.f, 0.f};
    float psacc = 0.f;

    for (int jt = 0; jt < 16; ++jt) {
        const short8 g0 = *(const short8*)&hTb[(size_t)c * 1024 + jt * 64 + m2 * 16];
        const short8 g1 = *(const short8*)&hTb[(size_t)c * 1024 + jt * 64 + m2 * 16 + 8];
        const float4 sd4 = *(const float4*)&sd[jt * 64 + jq * 4];
        const unsigned bits = mrow[jt * 2 + (jq >> 3)] >> ((jq & 7) * 4);

        __syncthreads();                      // prev tile's MFMA reads done
        *(short8*)&h_u[hw0] = g0;
        *(short8*)&h_u[hw1] = g1;

        float e0 = ssq + sd4.x; e0 = e0 > 0.f ? e0 : ALPHA * e0;
        float e1 = ssq + sd4.y; e1 = e1 > 0.f ? e1 : ALPHA * e1;
        float e2 = ssq + sd4.z; e2 = e2 > 0.f ? e2 : ALPHA * e2;
        float e3 = ssq + sd4.w; e3 = e3 > 0.f ? e3 : ALPHA * e3;
        const float p0 = (bits & 1u) ? __expf(e0) : 0.f;
        const float p1 = (bits & 2u) ? __expf(e1) : 0.f;
        const float p2 = (bits & 4u) ? __expf(e2) : 0.f;
        const float p3 = (bits & 8u) ? __expf(e3) : 0.f;
        psacc += (p0 + p1) + (p2 + p3);
        const uint2 pw = {f32bf(p0) | (f32bf(p1) << 16), f32bf(p2) | (f32bf(p3) << 16)};
        *(uint2*)&p_u[pwi] = pw;
        __syncthreads();                      // p and h tiles visible

#pragma unroll
        for (int t = 0; t < 2; ++t) {
            const short8 af = *(const short8*)&p_u[fa_ii * 64 + ((t * 4 + fq) ^ (fa_ii & 7)) * 8];
            const short8 bf = *(const short8*)&h_u[cB * 64 + ((t * 4 + fq) ^ (cB & 7)) * 8];
            acc = __builtin_amdgcn_mfma_f32_16x16x32_bf16(af, bf, acc, 0, 0, 0);
        }
    }

    // psum: reduce within 16-lane groups (threads sharing ii)
#pragma unroll
    for (int off = 1; off < 16; off <<= 1) psacc += __shfl_xor(psacc, off, 64);
    if ((tid & 15) == 0) psum_s[ii] = psacc;
    __syncthreads();

#pragma unroll
    for (int r = 0; r < 4; ++r) {
        const int row = fq * 4 + r;                        // C/D: row=(lane>>4)*4+r, col=lane&15
        const float hp = acc[r] / psum_s[row];
        const float o = hp > 0.f ? hp : __expf(hp) - 1.f;  // ELU
        out[((size_t)(b * N + i0 + row)) * 64 + wave * 16 + (lane & 15)] = o;
    }
}

extern "C" void kernel_launch(void* const* d_in, const int* in_sizes, int n_in,
                              void* d_out, int out_size, void* d_ws, size_t ws_size,
                              hipStream_t stream) {
    const float* input = (const float*)d_in[0];
    const float* adj   = (const float*)d_in[1];
    const float* Wm    = (const float*)d_in[2];
    const float* a     = (const float*)d_in[3];
    float* out = (float*)d_out;

    char* ws = (char*)d_ws;
    unsigned short* hT = (unsigned short*)ws;                      // 4 MB
    float* ssrc = (float*)(ws + 4194304);                          // 128 KB
    float* sdst = (float*)(ws + 4194304 + 131072);                 // 128 KB
    unsigned long long* mask64 = (unsigned long long*)(ws + 4194304 + 2 * 131072);  // 128 KB
    float* wa = (float*)(ws + 4194304 + 3 * 131072);               // 512 B

    gat_mask<<<N * N / 64 / 4, 256, 0, stream>>>(adj, Wm, a, mask64, wa);
    gat_hs<<<B * N / 64, 256, 0, stream>>>(input, Wm, wa, hT, ssrc, sdst);
    gat_attn<<<(N / TI) * B, 256, 0, stream>>>(hT, ssrc, sdst, (const unsigned*)mask64, out);
}